// Round 1
// baseline (362.337 us; speedup 1.0000x reference)
//
#include <hip/hip_runtime.h>
#include <hip/hip_bf16.h>
#include <stdint.h>

#define B_ROWS 16384
#define D_IN   512
#define H_DIM  1024
#define K_TOT  1536
#define NG     4096   // 4 gates * H

typedef __attribute__((ext_vector_type(8))) short  bf16x8;
typedef __attribute__((ext_vector_type(4))) float  f32x4;
typedef __attribute__((ext_vector_type(4))) float  float4v;
typedef __attribute__((ext_vector_type(8))) unsigned short u16x8;

__device__ __forceinline__ unsigned short f2bf(float f) {
    uint32_t u = __float_as_uint(f);
    u = (u + 0x7FFFu + ((u >> 16) & 1u)) >> 16;   // RNE
    return (unsigned short)u;
}

// ---------------------------------------------------------------------------
// A[r][k] bf16 : k in [0,512) = x[r][k] ; k in [512,1536) = h_old[r][k-512]
// one thread per 8 elements; 16384*192 threads total
// ---------------------------------------------------------------------------
__global__ void cvt_A(const float* __restrict__ x, const float* __restrict__ h,
                      unsigned short* __restrict__ A) {
    int t   = blockIdx.x * blockDim.x + threadIdx.x;
    int row = t / 192;
    int seg = t % 192;
    const float* src;
    if (seg < 64) src = x + (size_t)row * D_IN + seg * 8;
    else          src = h + (size_t)row * H_DIM + (seg - 64) * 8;
    float4v v0 = *(const float4v*)(src);
    float4v v1 = *(const float4v*)(src + 4);
    u16x8 o;
    o[0] = f2bf(v0[0]); o[1] = f2bf(v0[1]); o[2] = f2bf(v0[2]); o[3] = f2bf(v0[3]);
    o[4] = f2bf(v1[0]); o[5] = f2bf(v1[1]); o[6] = f2bf(v1[2]); o[7] = f2bf(v1[3]);
    *(u16x8*)(A + (size_t)row * K_TOT + seg * 8) = o;
}

// ---------------------------------------------------------------------------
// Bg[c][k] bf16, c in [0,4096): gate-interleaved column layout:
//   hg = c>>6, gate = (c>>4)&3, h = hg*16 + (c&15)
//   k<512 -> Ugate_w[k][h] ; else Wgate_w[k-512][h]
// one thread per 8 k's; 4096*192 threads
// ---------------------------------------------------------------------------
__global__ void cvt_B(const float* __restrict__ Ui, const float* __restrict__ Uf,
                      const float* __restrict__ Uo, const float* __restrict__ Uc,
                      const float* __restrict__ Wi, const float* __restrict__ Wf,
                      const float* __restrict__ Wo, const float* __restrict__ Wc,
                      unsigned short* __restrict__ Bg) {
    int t  = blockIdx.x * blockDim.x + threadIdx.x;
    int c  = t / 192;
    int k8 = t % 192;
    int g  = (c >> 4) & 3;
    int h  = ((c >> 6) << 4) | (c & 15);
    const float* up = (g == 0) ? Ui : (g == 1) ? Uf : (g == 2) ? Uo : Uc;
    const float* wp = (g == 0) ? Wi : (g == 1) ? Wf : (g == 2) ? Wo : Wc;
    int k = k8 * 8;
    u16x8 o;
    if (k < 512) {
        const float* s = up + (size_t)k * H_DIM + h;
        #pragma unroll
        for (int i = 0; i < 8; ++i) o[i] = f2bf(s[(size_t)i * H_DIM]);
    } else {
        const float* s = wp + (size_t)(k - 512) * H_DIM + h;
        #pragma unroll
        for (int i = 0; i < 8; ++i) o[i] = f2bf(s[(size_t)i * H_DIM]);
    }
    *(u16x8*)(Bg + (size_t)c * K_TOT + k) = o;
}

// combined bias[g*1024 + h] = U<g>_b[h] + W<g>_b[h]; 4096 threads
__global__ void cvt_bias(const float* __restrict__ Uib, const float* __restrict__ Ufb,
                         const float* __restrict__ Uob, const float* __restrict__ Ucb,
                         const float* __restrict__ Wib, const float* __restrict__ Wfb,
                         const float* __restrict__ Wob, const float* __restrict__ Wcb,
                         float* __restrict__ bias) {
    int t = blockIdx.x * blockDim.x + threadIdx.x;
    int g = t >> 10, h = t & 1023;
    const float* ub = (g == 0) ? Uib : (g == 1) ? Ufb : (g == 2) ? Uob : Ucb;
    const float* wb = (g == 0) ? Wib : (g == 1) ? Wfb : (g == 2) ? Wob : Wcb;
    bias[t] = ub[h] + wb[h];
}

// ---------------------------------------------------------------------------
// Fused GEMM + LSTM epilogue.
// Tile: 128 rows x 128 gate-cols (= 32 h x 4 gates), BK=32, 4 waves.
// Wave w: rows (w&1)*64, cols (w>>1)*64 -> acc[4][4] of 16x16 frags.
// Column layout within 64-col block: gate*16 + h_in, so each lane's 4 n-frags
// are gates {i,f,o,c} for one h -> fully in-lane LSTM elementwise.
// ---------------------------------------------------------------------------
__global__ __launch_bounds__(256) void lstm_gemm(
        const unsigned short* __restrict__ Ag, const unsigned short* __restrict__ Bg,
        const float* __restrict__ bias, const float* __restrict__ c_old,
        float* __restrict__ out) {
    __shared__ __align__(16) unsigned short Alds[128 * 32];
    __shared__ __align__(16) unsigned short Blds[128 * 32];

    const int tid = threadIdx.x;
    const int l   = tid & 63;
    const int w   = tid >> 6;
    const int bn  = blockIdx.x & 31;   // 32 N-tiles (each 32 h)
    const int bm  = blockIdx.x >> 5;   // 128 M-tiles
    const int wr  = w & 1;
    const int wc  = w >> 1;

    // staging: each wave stages 32 rows of A and 32 rows of B^T (2 loads each)
    const int srow = l >> 2;           // 0..15
    const int scol = (l & 3) * 8;      // k element offset (16B granules)
    const unsigned short* aSrc = Ag + (size_t)(bm * 128 + w * 32 + srow) * K_TOT + scol;
    const unsigned short* bSrc = Bg + (size_t)(bn * 128 + w * 32 + srow) * K_TOT + scol;
    unsigned short* aDst = Alds + (w * 32) * 32;
    unsigned short* bDst = Blds + (w * 32) * 32;

    const unsigned short* ap = Alds + (wr * 64 + (l & 15)) * 32 + (l >> 4) * 8;
    const unsigned short* bp = Blds + (wc * 64 + (l & 15)) * 32 + (l >> 4) * 8;

    f32x4 acc[4][4] = {};

    for (int k0 = 0; k0 < K_TOT; k0 += 32) {
        __syncthreads();
        #pragma unroll
        for (int q = 0; q < 2; ++q) {
            __builtin_amdgcn_global_load_lds(
                (const __attribute__((address_space(1))) void*)(aSrc + (size_t)(q * 16) * K_TOT + k0),
                (__attribute__((address_space(3))) void*)(aDst + q * 16 * 32), 16, 0, 0);
            __builtin_amdgcn_global_load_lds(
                (const __attribute__((address_space(1))) void*)(bSrc + (size_t)(q * 16) * K_TOT + k0),
                (__attribute__((address_space(3))) void*)(bDst + q * 16 * 32), 16, 0, 0);
        }
        __syncthreads();

        bf16x8 a[4], b[4];
        #pragma unroll
        for (int m = 0; m < 4; ++m) a[m] = *(const bf16x8*)(ap + m * 16 * 32);
        #pragma unroll
        for (int n = 0; n < 4; ++n) b[n] = *(const bf16x8*)(bp + n * 16 * 32);

        #pragma unroll
        for (int m = 0; m < 4; ++m)
            #pragma unroll
            for (int n = 0; n < 4; ++n)
                acc[m][n] = __builtin_amdgcn_mfma_f32_16x16x32_bf16(a[m], b[n], acc[m][n], 0, 0, 0);
    }

    // ---- fused LSTM epilogue (all 4 gates in-lane) ----
    const int hh  = bn * 32 + wc * 16 + (l & 15);
    const float bi  = bias[hh];
    const float bff = bias[1024 + hh];
    const float bo  = bias[2048 + hh];
    const float bc  = bias[3072 + hh];

    #pragma unroll
    for (int m = 0; m < 4; ++m) {
        const int rb = bm * 128 + wr * 64 + m * 16 + ((l >> 4) * 4);
        #pragma unroll
        for (int j = 0; j < 4; ++j) {
            const int r = rb + j;
            float iv = acc[m][0][j] + bi;
            float fv = acc[m][1][j] + bff;
            float ov = acc[m][2][j] + bo;
            float gv = acc[m][3][j] + bc;
            float it = 1.f / (1.f + __expf(-iv));
            float ft = 1.f / (1.f + __expf(-fv));
            float ot = 1.f / (1.f + __expf(-ov));
            float gt = 1.f - 2.f / (1.f + __expf(2.f * gv));
            float co = c_old[(size_t)r * H_DIM + hh];
            float cn = it * gt + ft * co;
            float th = 1.f - 2.f / (1.f + __expf(2.f * cn));
            out[(size_t)r * H_DIM + hh]                      = ot * th;   // h_new
            out[(size_t)(B_ROWS) * H_DIM + (size_t)r * H_DIM + hh] = cn;  // c
        }
    }
}

extern "C" void kernel_launch(void* const* d_in, const int* in_sizes, int n_in,
                              void* d_out, int out_size, void* d_ws, size_t ws_size,
                              hipStream_t stream) {
    const float* x  = (const float*)d_in[0];
    const float* h0 = (const float*)d_in[1];
    const float* c0 = (const float*)d_in[2];
    // dict order: Ui_w,Ui_b,Uf_w,Uf_b,Uo_w,Uo_b,Uc_w,Uc_b, then W same pattern
    const float* Uw[4] = {(const float*)d_in[3],  (const float*)d_in[5],
                          (const float*)d_in[7],  (const float*)d_in[9]};
    const float* Ub[4] = {(const float*)d_in[4],  (const float*)d_in[6],
                          (const float*)d_in[8],  (const float*)d_in[10]};
    const float* Ww[4] = {(const float*)d_in[11], (const float*)d_in[13],
                          (const float*)d_in[15], (const float*)d_in[17]};
    const float* Wb[4] = {(const float*)d_in[12], (const float*)d_in[14],
                          (const float*)d_in[16], (const float*)d_in[18]};

    unsigned short* Ag = (unsigned short*)d_ws;                       // 50,331,648 B
    unsigned short* Bg = Ag + (size_t)B_ROWS * K_TOT;                 // 12,582,912 B
    float* bias        = (float*)(Bg + (size_t)NG * K_TOT);           // 16,384 B
    float* out         = (float*)d_out;

    cvt_A<<<12288, 256, 0, stream>>>(x, h0, Ag);
    cvt_B<<<3072, 256, 0, stream>>>(Uw[0], Uw[1], Uw[2], Uw[3],
                                    Ww[0], Ww[1], Ww[2], Ww[3], Bg);
    cvt_bias<<<16, 256, 0, stream>>>(Ub[0], Ub[1], Ub[2], Ub[3],
                                     Wb[0], Wb[1], Wb[2], Wb[3], bias);
    lstm_gemm<<<4096, 256, 0, stream>>>(Ag, Bg, bias, c0, out);
}

// Round 2
// 295.361 us; speedup vs baseline: 1.2268x; 1.2268x over previous
//
#include <hip/hip_runtime.h>
#include <hip/hip_bf16.h>
#include <stdint.h>

#define B_ROWS 16384
#define D_IN   512
#define H_DIM  1024
#define K_TOT  1536
#define NT     24          // K-tiles of 64
#define NIT    12          // main-loop iterations (2 tiles each)

typedef __attribute__((ext_vector_type(8))) short  bf16x8;
typedef __attribute__((ext_vector_type(4))) float  f32x4;
typedef __attribute__((ext_vector_type(4))) float  float4v;
typedef __attribute__((ext_vector_type(8))) unsigned short u16x8;

__device__ __forceinline__ unsigned short f2bf(float f) {
    uint32_t u = __float_as_uint(f);
    u = (u + 0x7FFFu + ((u >> 16) & 1u)) >> 16;   // RNE
    return (unsigned short)u;
}

// ---------------------------------------------------------------------------
// A[r][k] bf16 : k in [0,512) = x[r][k] ; k in [512,1536) = h_old[r][k-512]
// ---------------------------------------------------------------------------
__global__ void cvt_A(const float* __restrict__ x, const float* __restrict__ h,
                      unsigned short* __restrict__ A) {
    int t   = blockIdx.x * blockDim.x + threadIdx.x;
    int row = t / 192;
    int seg = t % 192;
    const float* src;
    if (seg < 64) src = x + (size_t)row * D_IN + seg * 8;
    else          src = h + (size_t)row * H_DIM + (seg - 64) * 8;
    float4v v0 = *(const float4v*)(src);
    float4v v1 = *(const float4v*)(src + 4);
    u16x8 o;
    o[0] = f2bf(v0[0]); o[1] = f2bf(v0[1]); o[2] = f2bf(v0[2]); o[3] = f2bf(v0[3]);
    o[4] = f2bf(v1[0]); o[5] = f2bf(v1[1]); o[6] = f2bf(v1[2]); o[7] = f2bf(v1[3]);
    *(u16x8*)(A + (size_t)row * K_TOT + seg * 8) = o;
}

// ---------------------------------------------------------------------------
// Bg[c][k] bf16, c in [0,4096): gate-interleaved columns:
//   hg = c>>6, gate = (c>>4)&3, h = hg*16 + (c&15)
// ---------------------------------------------------------------------------
__global__ void cvt_B(const float* __restrict__ Ui, const float* __restrict__ Uf,
                      const float* __restrict__ Uo, const float* __restrict__ Uc,
                      const float* __restrict__ Wi, const float* __restrict__ Wf,
                      const float* __restrict__ Wo, const float* __restrict__ Wc,
                      unsigned short* __restrict__ Bg) {
    int t  = blockIdx.x * blockDim.x + threadIdx.x;
    int c  = t / 192;
    int k8 = t % 192;
    int g  = (c >> 4) & 3;
    int h  = ((c >> 6) << 4) | (c & 15);
    const float* up = (g == 0) ? Ui : (g == 1) ? Uf : (g == 2) ? Uo : Uc;
    const float* wp = (g == 0) ? Wi : (g == 1) ? Wf : (g == 2) ? Wo : Wc;
    int k = k8 * 8;
    u16x8 o;
    if (k < 512) {
        const float* s = up + (size_t)k * H_DIM + h;
        #pragma unroll
        for (int i = 0; i < 8; ++i) o[i] = f2bf(s[(size_t)i * H_DIM]);
    } else {
        const float* s = wp + (size_t)(k - 512) * H_DIM + h;
        #pragma unroll
        for (int i = 0; i < 8; ++i) o[i] = f2bf(s[(size_t)i * H_DIM]);
    }
    *(u16x8*)(Bg + (size_t)c * K_TOT + k) = o;
}

__global__ void cvt_bias(const float* __restrict__ Uib, const float* __restrict__ Ufb,
                         const float* __restrict__ Uob, const float* __restrict__ Ucb,
                         const float* __restrict__ Wib, const float* __restrict__ Wfb,
                         const float* __restrict__ Wob, const float* __restrict__ Wcb,
                         float* __restrict__ bias) {
    int t = blockIdx.x * blockDim.x + threadIdx.x;
    int g = t >> 10, h = t & 1023;
    const float* ub = (g == 0) ? Uib : (g == 1) ? Ufb : (g == 2) ? Uob : Ucb;
    const float* wb = (g == 0) ? Wib : (g == 1) ? Wfb : (g == 2) ? Wob : Wcb;
    bias[t] = ub[h] + wb[h];
}

// ---------------------------------------------------------------------------
// 256x256 8-phase deep-pipelined GEMM + fused LSTM epilogue.
// LDS regions (16 KiB each = 256 rows x 32 k bf16, swizzled):
//   base(buf,mat,q) = buf*65536 + mat*32768 + q*16384
// Physical layout within a region: byte = pair*128 + P*16, pair = row>>1,
//   P = ((row&1)*4 + (k>>3)) ^ (pair&7)   (XOR swizzle -> 2-way max conflict)
// global_load_lds writes linearly; the global SOURCE is inverse-swizzled.
// ---------------------------------------------------------------------------
__global__ __launch_bounds__(512, 2) void lstm_gemm(
        const unsigned short* __restrict__ Ag, const unsigned short* __restrict__ Bg,
        const float* __restrict__ bias, const float* __restrict__ c_old,
        float* __restrict__ out) {
    __shared__ __align__(1024) char lds[131072];

    const int tid = threadIdx.x;
    const int l   = tid & 63;
    const int wv  = tid >> 6;
    const int wr  = wv >> 2;      // M half (0..1)
    const int wcn = wv & 3;       // N quarter (0..3)

    const int orig = blockIdx.x;                    // 1024 blocks, 1024%8==0
    const int wg   = (orig & 7) * 128 + (orig >> 3);
    const int bm   = wg & 63;
    const int bn   = wg >> 6;

    // ---- staging source addresses (pre-swizzled global) ----
    const int Lx   = (l & 7) ^ (l >> 3);
    const int kel  = (Lx & 3) * 8;
    const int rloc = (l >> 3) * 2 + (Lx >> 2);
    const int rr0  = (wv * 2 + 0) * 16 + rloc;
    const int rr1  = (wv * 2 + 1) * 16 + rloc;
    const unsigned short* aS0 = Ag + (size_t)(bm * 256 + rr0) * K_TOT + kel;
    const unsigned short* aS1 = Ag + (size_t)(bm * 256 + rr1) * K_TOT + kel;
    const unsigned short* bS0 = Bg + (size_t)(bn * 256 + rr0) * K_TOT + kel;
    const unsigned short* bS1 = Bg + (size_t)(bn * 256 + rr1) * K_TOT + kel;

    // ---- swizzled LDS read offsets within a region ----
    int aoff[8], boff[4];
    #pragma unroll
    for (int m = 0; m < 8; ++m) {
        int ra = wr * 128 + m * 16 + (l & 15);
        aoff[m] = (ra >> 1) * 128 + ((((ra & 1) * 4 + (l >> 4)) ^ ((ra >> 1) & 7)) << 4);
    }
    #pragma unroll
    for (int n = 0; n < 4; ++n) {
        int rb = wcn * 64 + n * 16 + (l & 15);
        boff[n] = (rb >> 1) * 128 + ((((rb & 1) * 4 + (l >> 4)) ^ ((rb >> 1) & 7)) << 4);
    }

#define STAGE(MAT, TILE, Q, BUF) do {                                               \
    const unsigned short* _s0 = ((MAT) ? bS0 : aS0) + ((TILE) * 64 + (Q) * 32);     \
    const unsigned short* _s1 = ((MAT) ? bS1 : aS1) + ((TILE) * 64 + (Q) * 32);     \
    char* _d = (char*)lds + (BUF) * 65536 + (MAT) * 32768 + (Q) * 16384 + wv * 2048;\
    __builtin_amdgcn_global_load_lds(                                               \
        (const __attribute__((address_space(1))) void*)_s0,                         \
        (__attribute__((address_space(3))) void*)_d, 16, 0, 0);                     \
    __builtin_amdgcn_global_load_lds(                                               \
        (const __attribute__((address_space(1))) void*)_s1,                         \
        (__attribute__((address_space(3))) void*)(_d + 1024), 16, 0, 0);            \
} while (0)

    f32x4 acc[8][4] = {};
    bf16x8 bfr[4];

#define PHASE(BUF, Q, H, READB, SMAT, STILE, SQ, SBUF, DOVM) do {                   \
    const char* _ab = (const char*)lds + (BUF) * 65536 + (Q) * 16384;               \
    bf16x8 _a0 = *(const bf16x8*)(_ab + aoff[(H) * 4 + 0]);                         \
    bf16x8 _a1 = *(const bf16x8*)(_ab + aoff[(H) * 4 + 1]);                         \
    bf16x8 _a2 = *(const bf16x8*)(_ab + aoff[(H) * 4 + 2]);                         \
    bf16x8 _a3 = *(const bf16x8*)(_ab + aoff[(H) * 4 + 3]);                         \
    if (READB) {                                                                    \
        const char* _bb = _ab + 32768;                                              \
        bfr[0] = *(const bf16x8*)(_bb + boff[0]);                                   \
        bfr[1] = *(const bf16x8*)(_bb + boff[1]);                                   \
        bfr[2] = *(const bf16x8*)(_bb + boff[2]);                                   \
        bfr[3] = *(const bf16x8*)(_bb + boff[3]);                                   \
    }                                                                               \
    STAGE(SMAT, STILE, SQ, SBUF);                                                   \
    __builtin_amdgcn_s_setprio(1);                                                  \
    acc[(H)*4+0][0] = __builtin_amdgcn_mfma_f32_16x16x32_bf16(_a0, bfr[0], acc[(H)*4+0][0], 0, 0, 0); \
    acc[(H)*4+0][1] = __builtin_amdgcn_mfma_f32_16x16x32_bf16(_a0, bfr[1], acc[(H)*4+0][1], 0, 0, 0); \
    acc[(H)*4+0][2] = __builtin_amdgcn_mfma_f32_16x16x32_bf16(_a0, bfr[2], acc[(H)*4+0][2], 0, 0, 0); \
    acc[(H)*4+0][3] = __builtin_amdgcn_mfma_f32_16x16x32_bf16(_a0, bfr[3], acc[(H)*4+0][3], 0, 0, 0); \
    acc[(H)*4+1][0] = __builtin_amdgcn_mfma_f32_16x16x32_bf16(_a1, bfr[0], acc[(H)*4+1][0], 0, 0, 0); \
    acc[(H)*4+1][1] = __builtin_amdgcn_mfma_f32_16x16x32_bf16(_a1, bfr[1], acc[(H)*4+1][1], 0, 0, 0); \
    acc[(H)*4+1][2] = __builtin_amdgcn_mfma_f32_16x16x32_bf16(_a1, bfr[2], acc[(H)*4+1][2], 0, 0, 0); \
    acc[(H)*4+1][3] = __builtin_amdgcn_mfma_f32_16x16x32_bf16(_a1, bfr[3], acc[(H)*4+1][3], 0, 0, 0); \
    acc[(H)*4+2][0] = __builtin_amdgcn_mfma_f32_16x16x32_bf16(_a2, bfr[0], acc[(H)*4+2][0], 0, 0, 0); \
    acc[(H)*4+2][1] = __builtin_amdgcn_mfma_f32_16x16x32_bf16(_a2, bfr[1], acc[(H)*4+2][1], 0, 0, 0); \
    acc[(H)*4+2][2] = __builtin_amdgcn_mfma_f32_16x16x32_bf16(_a2, bfr[2], acc[(H)*4+2][2], 0, 0, 0); \
    acc[(H)*4+2][3] = __builtin_amdgcn_mfma_f32_16x16x32_bf16(_a2, bfr[3], acc[(H)*4+2][3], 0, 0, 0); \
    acc[(H)*4+3][0] = __builtin_amdgcn_mfma_f32_16x16x32_bf16(_a3, bfr[0], acc[(H)*4+3][0], 0, 0, 0); \
    acc[(H)*4+3][1] = __builtin_amdgcn_mfma_f32_16x16x32_bf16(_a3, bfr[1], acc[(H)*4+3][1], 0, 0, 0); \
    acc[(H)*4+3][2] = __builtin_amdgcn_mfma_f32_16x16x32_bf16(_a3, bfr[2], acc[(H)*4+3][2], 0, 0, 0); \
    acc[(H)*4+3][3] = __builtin_amdgcn_mfma_f32_16x16x32_bf16(_a3, bfr[3], acc[(H)*4+3][3], 0, 0, 0); \
    __builtin_amdgcn_s_setprio(0);                                                  \
    if (DOVM) { asm volatile("s_waitcnt vmcnt(8)\ns_barrier" ::: "memory"); }       \
    else      { asm volatile("s_barrier" ::: "memory"); }                           \
} while (0)

    // ---- prologue: T0 fully + T1.k0 (12 loads; oldest 4 = T0.A.k0,T0.B.k0) ----
    STAGE(0, 0, 0, 0); STAGE(1, 0, 0, 0);
    STAGE(0, 0, 1, 0); STAGE(1, 0, 1, 0);
    STAGE(0, 1, 0, 1); STAGE(1, 1, 0, 1);
    asm volatile("s_waitcnt vmcnt(8)\ns_barrier" ::: "memory");

    // ---- main loop: iteration i computes tiles 2i (buf0) and 2i+1 (buf1) ----
    #pragma unroll 1
    for (int i = 0; i < NIT; ++i) {
        const int t1 = 2 * i + 1;
        int t2 = 2 * i + 2; if (t2 >= NT) t2 = 0;   // clamped stagings are never read
        int t3 = 2 * i + 3; if (t3 >= NT) t3 = 0;
        PHASE(0, 0, 0, 1, 0, t1, 1, 1, 0);   // compute T0.q0.h0 ; stage A t1.k1 -> buf1
        PHASE(0, 0, 1, 0, 1, t1, 1, 1, 1);   //         q0.h1   ; stage B t1.k1 ; vmcnt
        PHASE(0, 1, 0, 1, 0, t2, 0, 0, 0);   //         q1.h0   ; stage A t2.k0 -> buf0
        PHASE(0, 1, 1, 0, 1, t2, 0, 0, 1);   //         q1.h1   ; stage B t2.k0 ; vmcnt
        PHASE(1, 0, 0, 1, 0, t2, 1, 0, 0);   // compute T1.q0.h0 ; stage A t2.k1 -> buf0
        PHASE(1, 0, 1, 0, 1, t2, 1, 0, 1);   //         q0.h1   ; stage B t2.k1 ; vmcnt
        PHASE(1, 1, 0, 1, 0, t3, 0, 1, 0);   //         q1.h0   ; stage A t3.k0 -> buf1
        PHASE(1, 1, 1, 0, 1, t3, 0, 1, 1);   //         q1.h1   ; stage B t3.k0 ; vmcnt
    }

    // ---- fused LSTM epilogue (4 gates in-lane across n) ----
    const int hh  = (bn * 4 + wcn) * 16 + (l & 15);
    const float bi  = bias[hh];
    const float bff = bias[1024 + hh];
    const float bo  = bias[2048 + hh];
    const float bc  = bias[3072 + hh];

    #pragma unroll
    for (int m = 0; m < 8; ++m) {
        const int rb = bm * 256 + wr * 128 + m * 16 + ((l >> 4) * 4);
        #pragma unroll
        for (int j = 0; j < 4; ++j) {
            const int r = rb + j;
            float iv = acc[m][0][j] + bi;
            float fv = acc[m][1][j] + bff;
            float ov = acc[m][2][j] + bo;
            float gv = acc[m][3][j] + bc;
            float it = 1.f / (1.f + __expf(-iv));
            float ft = 1.f / (1.f + __expf(-fv));
            float ot = 1.f / (1.f + __expf(-ov));
            float gt = 1.f - 2.f / (1.f + __expf(2.f * gv));
            float co = c_old[(size_t)r * H_DIM + hh];
            float cn = it * gt + ft * co;
            float th = 1.f - 2.f / (1.f + __expf(2.f * cn));
            out[(size_t)r * H_DIM + hh]                            = ot * th;  // h_new
            out[(size_t)B_ROWS * H_DIM + (size_t)r * H_DIM + hh]   = cn;       // c
        }
    }
#undef PHASE
#undef STAGE
}

extern "C" void kernel_launch(void* const* d_in, const int* in_sizes, int n_in,
                              void* d_out, int out_size, void* d_ws, size_t ws_size,
                              hipStream_t stream) {
    const float* x  = (const float*)d_in[0];
    const float* h0 = (const float*)d_in[1];
    const float* c0 = (const float*)d_in[2];
    const float* Uw[4] = {(const float*)d_in[3],  (const float*)d_in[5],
                          (const float*)d_in[7],  (const float*)d_in[9]};
    const float* Ub[4] = {(const float*)d_in[4],  (const float*)d_in[6],
                          (const float*)d_in[8],  (const float*)d_in[10]};
    const float* Ww[4] = {(const float*)d_in[11], (const float*)d_in[13],
                          (const float*)d_in[15], (const float*)d_in[17]};
    const float* Wb[4] = {(const float*)d_in[12], (const float*)d_in[14],
                          (const float*)d_in[16], (const float*)d_in[18]};

    unsigned short* Ag = (unsigned short*)d_ws;
    unsigned short* Bg = Ag + (size_t)B_ROWS * K_TOT;
    float* bias        = (float*)(Bg + (size_t)4096 * K_TOT);
    float* out         = (float*)d_out;

    cvt_A<<<12288, 256, 0, stream>>>(x, h0, Ag);
    cvt_B<<<3072, 256, 0, stream>>>(Uw[0], Uw[1], Uw[2], Uw[3],
                                    Ww[0], Ww[1], Ww[2], Ww[3], Bg);
    cvt_bias<<<16, 256, 0, stream>>>(Ub[0], Ub[1], Ub[2], Ub[3],
                                     Wb[0], Wb[1], Wb[2], Wb[3], bias);
    lstm_gemm<<<1024, 512, 0, stream>>>(Ag, Bg, bias, c0, out);
}

// Round 3
// 289.276 us; speedup vs baseline: 1.2526x; 1.0210x over previous
//
#include <hip/hip_runtime.h>
#include <hip/hip_bf16.h>
#include <stdint.h>

#define B_ROWS 16384
#define D_IN   512
#define H_DIM  1024
#define K_TOT  1536
#define NT     24          // K-tiles of 64
#define NIT    12          // main-loop iterations (2 tiles each)

typedef __attribute__((ext_vector_type(8))) short  bf16x8;
typedef __attribute__((ext_vector_type(4))) float  f32x4;
typedef __attribute__((ext_vector_type(4))) float  float4v;
typedef __attribute__((ext_vector_type(8))) unsigned short u16x8;

__device__ __forceinline__ unsigned short f2bf(float f) {
    uint32_t u = __float_as_uint(f);
    u = (u + 0x7FFFu + ((u >> 16) & 1u)) >> 16;   // RNE
    return (unsigned short)u;
}

// ---------------------------------------------------------------------------
// A[r][k] bf16 : k in [0,512) = x[r][k] ; k in [512,1536) = h_old[r][k-512]
// ---------------------------------------------------------------------------
__global__ void cvt_A(const float* __restrict__ x, const float* __restrict__ h,
                      unsigned short* __restrict__ A) {
    int t   = blockIdx.x * blockDim.x + threadIdx.x;
    int row = t / 192;
    int seg = t % 192;
    const float* src;
    if (seg < 64) src = x + (size_t)row * D_IN + seg * 8;
    else          src = h + (size_t)row * H_DIM + (seg - 64) * 8;
    float4v v0 = *(const float4v*)(src);
    float4v v1 = *(const float4v*)(src + 4);
    u16x8 o;
    o[0] = f2bf(v0[0]); o[1] = f2bf(v0[1]); o[2] = f2bf(v0[2]); o[3] = f2bf(v0[3]);
    o[4] = f2bf(v1[0]); o[5] = f2bf(v1[1]); o[6] = f2bf(v1[2]); o[7] = f2bf(v1[3]);
    *(u16x8*)(A + (size_t)row * K_TOT + seg * 8) = o;
}

// ---------------------------------------------------------------------------
// Bg[c][k] bf16, c in [0,4096): gate-interleaved columns:
//   hg = c>>6, gate = (c>>4)&3, h = hg*16 + (c&15)
// ---------------------------------------------------------------------------
__global__ void cvt_B(const float* __restrict__ Ui, const float* __restrict__ Uf,
                      const float* __restrict__ Uo, const float* __restrict__ Uc,
                      const float* __restrict__ Wi, const float* __restrict__ Wf,
                      const float* __restrict__ Wo, const float* __restrict__ Wc,
                      unsigned short* __restrict__ Bg) {
    int t  = blockIdx.x * blockDim.x + threadIdx.x;
    int c  = t / 192;
    int k8 = t % 192;
    int g  = (c >> 4) & 3;
    int h  = ((c >> 6) << 4) | (c & 15);
    const float* up = (g == 0) ? Ui : (g == 1) ? Uf : (g == 2) ? Uo : Uc;
    const float* wp = (g == 0) ? Wi : (g == 1) ? Wf : (g == 2) ? Wo : Wc;
    int k = k8 * 8;
    u16x8 o;
    if (k < 512) {
        const float* s = up + (size_t)k * H_DIM + h;
        #pragma unroll
        for (int i = 0; i < 8; ++i) o[i] = f2bf(s[(size_t)i * H_DIM]);
    } else {
        const float* s = wp + (size_t)(k - 512) * H_DIM + h;
        #pragma unroll
        for (int i = 0; i < 8; ++i) o[i] = f2bf(s[(size_t)i * H_DIM]);
    }
    *(u16x8*)(Bg + (size_t)c * K_TOT + k) = o;
}

__global__ void cvt_bias(const float* __restrict__ Uib, const float* __restrict__ Ufb,
                         const float* __restrict__ Uob, const float* __restrict__ Ucb,
                         const float* __restrict__ Wib, const float* __restrict__ Wfb,
                         const float* __restrict__ Wob, const float* __restrict__ Wcb,
                         float* __restrict__ bias) {
    int t = blockIdx.x * blockDim.x + threadIdx.x;
    int g = t >> 10, h = t & 1023;
    const float* ub = (g == 0) ? Uib : (g == 1) ? Ufb : (g == 2) ? Uob : Ucb;
    const float* wb = (g == 0) ? Wib : (g == 1) ? Wfb : (g == 2) ? Wob : Wcb;
    bias[t] = ub[h] + wb[h];
}

// ---------------------------------------------------------------------------
// 256x256 C-quadrant-phased GEMM + fused LSTM epilogue.
// LDS: 2 bufs x {A,B} regions of 32 KiB (256 phys-rows x 64 k bf16).
//   region byte(pr, kg) = pr*128 + ((kg ^ (pr&7)) << 4)   kg = k>>3
// Physical row order groups staging-halves:
//   A: pr = (stripe&1)*128 + (stripe>>1)*64 + (row&63),  stripe = row>>6
//   B: pr = (stripe&1)*128 + (stripe>>1)*32 + (row&31),  stripe = row>>5
// Staging writes linearly (dest = half*16K + wv*2048 + i*1024 + lane*16);
// the per-lane GLOBAL source row/kg realizes the swizzle (rule 21).
// Each stage instruction reads 8 rows x 128B contiguous (full L2 lines).
// Phases = C-quadrants (mq,nq), full K=64: A-half mq free after ph2,
// B-half nq0 after ph3 -> stage 1 half/phase, vmcnt(6)@ph1, vmcnt(8)@ph4.
// ---------------------------------------------------------------------------
__global__ __launch_bounds__(512, 2) void lstm_gemm(
        const unsigned short* __restrict__ Ag, const unsigned short* __restrict__ Bg,
        const float* __restrict__ bias, const float* __restrict__ c_old,
        float* __restrict__ out) {
    __shared__ __align__(1024) char lds[131072];

    const int tid = threadIdx.x;
    const int l   = tid & 63;
    const int wv  = tid >> 6;
    const int wr  = wv >> 2;      // M half (0..1)
    const int wcn = wv & 3;       // N quarter (0..3)

    // XCD-aware swizzle: each XCD's concurrent 32 blocks = 8 bm x 4 bn
    const int orig = blockIdx.x;            // 1024 blocks
    const int xcd  = orig & 7;
    const int jj   = orig >> 3;             // 0..127
    const int bn   = (xcd & 3) * 4 + (jj & 3);
    const int bm   = (xcd >> 2) * 32 + (jj >> 2);

    // ---- staging source pointers (pre-swizzled global, rule 21) ----
    const int kg   = (l & 7) ^ (l >> 3);
    const int rel0 = wv * 16 + (l >> 3);        // i=0 physical row
    const int rel1 = rel0 + 8;                  // i=1
    // invert physical-row -> matrix-row (h added per STAGE)
    const int rA0 = ((rel0 >> 6) << 7) + (rel0 & 63);
    const int rA1 = ((rel1 >> 6) << 7) + (rel1 & 63);
    const int rB0 = ((rel0 >> 5) << 6) + (rel0 & 31);
    const int rB1 = ((rel1 >> 5) << 6) + (rel1 & 31);
    const unsigned short* aP0 = Ag + (size_t)(bm * 256 + rA0) * K_TOT + kg * 8;
    const unsigned short* aP1 = Ag + (size_t)(bm * 256 + rA1) * K_TOT + kg * 8;
    const unsigned short* bP0 = Bg + (size_t)(bn * 256 + rB0) * K_TOT + kg * 8;
    const unsigned short* bP1 = Bg + (size_t)(bn * 256 + rB1) * K_TOT + kg * 8;

    // ---- swizzled LDS read offsets (q=1 -> XOR 64) ----
    const int slot = ((l >> 4) ^ (l & 7)) << 4;
    int aoffb[8], boffb[4];
    #pragma unroll
    for (int mq = 0; mq < 2; ++mq)
        #pragma unroll
        for (int mm = 0; mm < 4; ++mm) {
            int pr = mq * 128 + wr * 64 + mm * 16 + (l & 15);
            aoffb[mq * 4 + mm] = pr * 128 + slot;
        }
    #pragma unroll
    for (int nq = 0; nq < 2; ++nq)
        #pragma unroll
        for (int nn = 0; nn < 2; ++nn) {
            int pr = nq * 128 + wcn * 32 + nn * 16 + (l & 15);
            boffb[nq * 2 + nn] = pr * 128 + slot;
        }

#define STAGE(MAT, TILE, HF, BUF) do {                                              \
    const unsigned short* _s0 = ((MAT) ? bP0 : aP0)                                 \
        + (size_t)((HF) * ((MAT) ? 32 : 64)) * K_TOT + (TILE) * 64;                 \
    const unsigned short* _s1 = ((MAT) ? bP1 : aP1)                                 \
        + (size_t)((HF) * ((MAT) ? 32 : 64)) * K_TOT + (TILE) * 64;                 \
    char* _d = (char*)lds + (BUF) * 65536 + (MAT) * 32768 + (HF) * 16384 + wv * 2048;\
    __builtin_amdgcn_global_load_lds(                                               \
        (const __attribute__((address_space(1))) void*)_s0,                         \
        (__attribute__((address_space(3))) void*)_d, 16, 0, 0);                     \
    __builtin_amdgcn_global_load_lds(                                               \
        (const __attribute__((address_space(1))) void*)_s1,                         \
        (__attribute__((address_space(3))) void*)(_d + 1024), 16, 0, 0);            \
} while (0)

    f32x4 acc[8][4] = {};

    // WAITK: 0 = plain barrier, else s_waitcnt vmcnt(WAITK) first
#define PHASE(BUF, MQ, NQ, SMAT, STILE, SHF, SBUF, WAITK) do {                      \
    const char* _Ab = (const char*)lds + (BUF) * 65536;                             \
    const char* _Bb = _Ab + 32768;                                                  \
    bf16x8 a00 = *(const bf16x8*)(_Ab + (aoffb[(MQ)*4+0]));                         \
    bf16x8 a01 = *(const bf16x8*)(_Ab + (aoffb[(MQ)*4+1]));                         \
    bf16x8 a02 = *(const bf16x8*)(_Ab + (aoffb[(MQ)*4+2]));                         \
    bf16x8 a03 = *(const bf16x8*)(_Ab + (aoffb[(MQ)*4+3]));                         \
    bf16x8 a10 = *(const bf16x8*)(_Ab + (aoffb[(MQ)*4+0] ^ 64));                    \
    bf16x8 a11 = *(const bf16x8*)(_Ab + (aoffb[(MQ)*4+1] ^ 64));                    \
    bf16x8 a12 = *(const bf16x8*)(_Ab + (aoffb[(MQ)*4+2] ^ 64));                    \
    bf16x8 a13 = *(const bf16x8*)(_Ab + (aoffb[(MQ)*4+3] ^ 64));                    \
    bf16x8 b00 = *(const bf16x8*)(_Bb + (boffb[(NQ)*2+0]));                         \
    bf16x8 b01 = *(const bf16x8*)(_Bb + (boffb[(NQ)*2+1]));                         \
    bf16x8 b10 = *(const bf16x8*)(_Bb + (boffb[(NQ)*2+0] ^ 64));                    \
    bf16x8 b11 = *(const bf16x8*)(_Bb + (boffb[(NQ)*2+1] ^ 64));                    \
    STAGE(SMAT, STILE, SHF, SBUF);                                                  \
    __builtin_amdgcn_s_setprio(1);                                                  \
    acc[(MQ)*4+0][(NQ)*2+0] = __builtin_amdgcn_mfma_f32_16x16x32_bf16(a00, b00, acc[(MQ)*4+0][(NQ)*2+0], 0, 0, 0); \
    acc[(MQ)*4+0][(NQ)*2+1] = __builtin_amdgcn_mfma_f32_16x16x32_bf16(a00, b01, acc[(MQ)*4+0][(NQ)*2+1], 0, 0, 0); \
    acc[(MQ)*4+1][(NQ)*2+0] = __builtin_amdgcn_mfma_f32_16x16x32_bf16(a01, b00, acc[(MQ)*4+1][(NQ)*2+0], 0, 0, 0); \
    acc[(MQ)*4+1][(NQ)*2+1] = __builtin_amdgcn_mfma_f32_16x16x32_bf16(a01, b01, acc[(MQ)*4+1][(NQ)*2+1], 0, 0, 0); \
    acc[(MQ)*4+2][(NQ)*2+0] = __builtin_amdgcn_mfma_f32_16x16x32_bf16(a02, b00, acc[(MQ)*4+2][(NQ)*2+0], 0, 0, 0); \
    acc[(MQ)*4+2][(NQ)*2+1] = __builtin_amdgcn_mfma_f32_16x16x32_bf16(a02, b01, acc[(MQ)*4+2][(NQ)*2+1], 0, 0, 0); \
    acc[(MQ)*4+3][(NQ)*2+0] = __builtin_amdgcn_mfma_f32_16x16x32_bf16(a03, b00, acc[(MQ)*4+3][(NQ)*2+0], 0, 0, 0); \
    acc[(MQ)*4+3][(NQ)*2+1] = __builtin_amdgcn_mfma_f32_16x16x32_bf16(a03, b01, acc[(MQ)*4+3][(NQ)*2+1], 0, 0, 0); \
    acc[(MQ)*4+0][(NQ)*2+0] = __builtin_amdgcn_mfma_f32_16x16x32_bf16(a10, b10, acc[(MQ)*4+0][(NQ)*2+0], 0, 0, 0); \
    acc[(MQ)*4+0][(NQ)*2+1] = __builtin_amdgcn_mfma_f32_16x16x32_bf16(a10, b11, acc[(MQ)*4+0][(NQ)*2+1], 0, 0, 0); \
    acc[(MQ)*4+1][(NQ)*2+0] = __builtin_amdgcn_mfma_f32_16x16x32_bf16(a11, b10, acc[(MQ)*4+1][(NQ)*2+0], 0, 0, 0); \
    acc[(MQ)*4+1][(NQ)*2+1] = __builtin_amdgcn_mfma_f32_16x16x32_bf16(a11, b11, acc[(MQ)*4+1][(NQ)*2+1], 0, 0, 0); \
    acc[(MQ)*4+2][(NQ)*2+0] = __builtin_amdgcn_mfma_f32_16x16x32_bf16(a12, b10, acc[(MQ)*4+2][(NQ)*2+0], 0, 0, 0); \
    acc[(MQ)*4+2][(NQ)*2+1] = __builtin_amdgcn_mfma_f32_16x16x32_bf16(a12, b11, acc[(MQ)*4+2][(NQ)*2+1], 0, 0, 0); \
    acc[(MQ)*4+3][(NQ)*2+0] = __builtin_amdgcn_mfma_f32_16x16x32_bf16(a13, b10, acc[(MQ)*4+3][(NQ)*2+0], 0, 0, 0); \
    acc[(MQ)*4+3][(NQ)*2+1] = __builtin_amdgcn_mfma_f32_16x16x32_bf16(a13, b11, acc[(MQ)*4+3][(NQ)*2+1], 0, 0, 0); \
    __builtin_amdgcn_s_setprio(0);                                                  \
    if ((WAITK) == 6)      { asm volatile("s_waitcnt vmcnt(6)\ns_barrier" ::: "memory"); } \
    else if ((WAITK) == 8) { asm volatile("s_waitcnt vmcnt(8)\ns_barrier" ::: "memory"); } \
    else                   { asm volatile("s_barrier" ::: "memory"); }              \
} while (0)

    // ---- prologue: A0h0,B0h0,B0h1,A0h1 -> buf0; A1h0,B1h0 -> buf1 ----
    STAGE(0, 0, 0, 0); STAGE(1, 0, 0, 0);
    STAGE(1, 0, 1, 0); STAGE(0, 0, 1, 0);
    STAGE(0, 1, 0, 1); STAGE(1, 1, 0, 1);
    asm volatile("s_waitcnt vmcnt(8)\ns_barrier" ::: "memory");

    // ---- main loop: tiles 2i (buf0) and 2i+1 (buf1) ----
    #pragma unroll 1
    for (int i = 0; i < NIT; ++i) {
        const int t1 = 2 * i + 1;
        int t2 = 2 * i + 2; if (t2 >= NT) t2 -= NT;   // wrapped stagings never read
        int t3 = 2 * i + 3; if (t3 >= NT) t3 -= NT;
        // tile 2i (buf0)
        PHASE(0, 0, 0,  0, t1, 1, 1,  6);   // stage A(t+1).h1 -> buf1
        PHASE(0, 0, 1,  1, t1, 1, 1,  0);   // stage B(t+1).h1 -> buf1
        PHASE(0, 1, 0,  0, t2, 0, 0,  0);   // stage A(t+2).h0 -> buf0
        PHASE(0, 1, 1,  1, t2, 0, 0,  8);   // stage B(t+2).h0 -> buf0
        // tile 2i+1 (buf1)
        PHASE(1, 0, 0,  0, t2, 1, 0,  6);   // stage A(t+2).h1 -> buf0
        PHASE(1, 0, 1,  1, t2, 1, 0,  0);   // stage B(t+2).h1 -> buf0
        PHASE(1, 1, 0,  0, t3, 0, 1,  0);   // stage A(t+3).h0 -> buf1
        PHASE(1, 1, 1,  1, t3, 0, 1,  8);   // stage B(t+3).h0 -> buf1
    }

    // ---- fused LSTM epilogue (4 gates in-lane across n) ----
    const int hh  = (bn * 4 + wcn) * 16 + (l & 15);
    const float bi  = bias[hh];
    const float bff = bias[1024 + hh];
    const float bo  = bias[2048 + hh];
    const float bc  = bias[3072 + hh];

    #pragma unroll
    for (int m = 0; m < 8; ++m) {
        const int rb = bm * 256 + wr * 128 + m * 16 + ((l >> 4) * 4);
        #pragma unroll
        for (int j = 0; j < 4; ++j) {
            const int r = rb + j;
            float iv = acc[m][0][j] + bi;
            float fv = acc[m][1][j] + bff;
            float ov = acc[m][2][j] + bo;
            float gv = acc[m][3][j] + bc;
            float it = 1.f / (1.f + __expf(-iv));
            float ft = 1.f / (1.f + __expf(-fv));
            float ot = 1.f / (1.f + __expf(-ov));
            float gt = 1.f - 2.f / (1.f + __expf(2.f * gv));
            float co = c_old[(size_t)r * H_DIM + hh];
            float cn = it * gt + ft * co;
            float th = 1.f - 2.f / (1.f + __expf(2.f * cn));
            out[(size_t)r * H_DIM + hh]                            = ot * th;  // h_new
            out[(size_t)B_ROWS * H_DIM + (size_t)r * H_DIM + hh]   = cn;       // c
        }
    }
#undef PHASE
#undef STAGE
}

extern "C" void kernel_launch(void* const* d_in, const int* in_sizes, int n_in,
                              void* d_out, int out_size, void* d_ws, size_t ws_size,
                              hipStream_t stream) {
    const float* x  = (const float*)d_in[0];
    const float* h0 = (const float*)d_in[1];
    const float* c0 = (const float*)d_in[2];
    const float* Uw[4] = {(const float*)d_in[3],  (const float*)d_in[5],
                          (const float*)d_in[7],  (const float*)d_in[9]};
    const float* Ub[4] = {(const float*)d_in[4],  (const float*)d_in[6],
                          (const float*)d_in[8],  (const float*)d_in[10]};
    const float* Ww[4] = {(const float*)d_in[11], (const float*)d_in[13],
                          (const float*)d_in[15], (const float*)d_in[17]};
    const float* Wb[4] = {(const float*)d_in[12], (const float*)d_in[14],
                          (const float*)d_in[16], (const float*)d_in[18]};

    unsigned short* Ag = (unsigned short*)d_ws;
    unsigned short* Bg = Ag + (size_t)B_ROWS * K_TOT;
    float* bias        = (float*)(Bg + (size_t)4096 * K_TOT);
    float* out         = (float*)d_out;

    cvt_A<<<12288, 256, 0, stream>>>(x, h0, Ag);
    cvt_B<<<3072, 256, 0, stream>>>(Uw[0], Uw[1], Uw[2], Uw[3],
                                    Ww[0], Ww[1], Ww[2], Ww[3], Bg);
    cvt_bias<<<16, 256, 0, stream>>>(Ub[0], Ub[1], Ub[2], Ub[3],
                                     Wb[0], Wb[1], Wb[2], Wb[3], bias);
    lstm_gemm<<<1024, 512, 0, stream>>>(Ag, Bg, bias, c0, out);
}